// Round 7
// baseline (217.571 us; speedup 1.0000x reference)
//
#include <hip/hip_runtime.h>
#include <hip/hip_bf16.h>
#include <stdint.h>

typedef __attribute__((ext_vector_type(8))) __bf16 bf16x8;
typedef __attribute__((ext_vector_type(4))) float f32x4;
typedef __attribute__((ext_vector_type(16))) float f32x16;
typedef unsigned short u16;

#define MFMA16(a, b, c) __builtin_amdgcn_mfma_f32_16x16x32_bf16((a), (b), (c), 0, 0, 0)
#define MFMA32(a, b, c) __builtin_amdgcn_mfma_f32_32x32x16_bf16((a), (b), (c), 0, 0, 0)

__device__ __forceinline__ u16 f32_to_bf16_rne(float f) {
  union { float f; uint32_t u; } v; v.f = f;
  uint32_t u = v.u;
  u += 0x7fffu + ((u >> 16) & 1u);
  return (u16)(u >> 16);
}

__device__ __forceinline__ float bf16_to_f32(u16 h) {
  union { uint32_t u; float f; } v; v.u = ((uint32_t)h) << 16;
  return v.f;
}

__device__ __forceinline__ void gl_lds16(const void* g, void* l) {
  __builtin_amdgcn_global_load_lds(
      (const __attribute__((address_space(1))) void*)(uintptr_t)g,
      (__attribute__((address_space(3))) void*)(uintptr_t)l,
      16, 0, 0);
}

__device__ __forceinline__ float fast_exp2(float x) {
#if __has_builtin(__builtin_amdgcn_exp2f)
  return __builtin_amdgcn_exp2f(x);
#else
  return exp2f(x);
#endif
}

__device__ __forceinline__ uint32_t cvt_pk_bf16(float a, float b) {
  uint32_t r;
  asm("v_cvt_pk_bf16_f32 %0, %1, %2" : "=v"(r) : "v"(a), "v"(b));
  return r;
}

// ---------------------------------------------------------------- fused cast
__global__ void cast_all_kernel(const float* __restrict__ x, const float* __restrict__ Wk,
                                const float* __restrict__ Wq, const float* __restrict__ Wv,
                                const float* __restrict__ Wo, u16* __restrict__ xb,
                                u16* __restrict__ wqkv, u16* __restrict__ wob) {
  const int i = blockIdx.x * 256 + threadIdx.x;
  const float* src; u16* dst; int off;
  if (i < 2097152)      { src = x;  dst = xb;             off = i; }
  else if (i < 2359296) { src = Wk; dst = wqkv;           off = i - 2097152; }
  else if (i < 2621440) { src = Wq; dst = wqkv + 1048576; off = i - 2359296; }
  else if (i < 2883584) { src = Wv; dst = wqkv + 2097152; off = i - 2621440; }
  else                  { src = Wo; dst = wob;            off = i - 2883584; }
  float4 v = reinterpret_cast<const float4*>(src)[off];
  ushort4 o;
  o.x = f32_to_bf16_rne(v.x);
  o.y = f32_to_bf16_rne(v.y);
  o.z = f32_to_bf16_rne(v.z);
  o.w = f32_to_bf16_rne(v.w);
  reinterpret_cast<ushort4*>(dst)[off] = o;
}

// ---------------------------------------------------------------- GEMM (B^T)
// C[m,n] = sum_k A[m,k]*Bt[n,k]. 128x128 tile, BK=32, 4 waves (2x2), 4x4 frags.
template <int FINAL>
__global__ __launch_bounds__(256, 2) void gemm_bt_kernel(
    const u16* __restrict__ A, const u16* __restrict__ Bt,
    void* __restrict__ Cout, const float* __restrict__ bias, int M, int N, int K) {
  __shared__ __attribute__((aligned(16))) u16 As[128 * 32];
  __shared__ __attribute__((aligned(16))) u16 Bs[128 * 32];
  const int tid = threadIdx.x;
  const int lane = tid & 63;
  const int wid = tid >> 6;
  const int wr = wid >> 1, wc = wid & 1;
  const int m0 = blockIdx.y * 128, n0 = blockIdx.x * 128;

  f32x4 acc[4][4] = {};

  const int sr = lane >> 2;
  const int scc = lane & 3;
  const int sh = (sr ^ (sr >> 2)) & 3;
  const int sc = ((scc ^ sh) << 3);
  const int rl = lane & 15;
  const int rh = (rl ^ (rl >> 2)) & 3;
  const int cpr = (((lane >> 4) ^ rh) << 4);

  for (int k0 = 0; k0 < K; k0 += 32) {
    __syncthreads();
#pragma unroll
    for (int i = 0; i < 2; ++i) {
      const int c = wid * 2 + i;
      const int row = c * 16 + sr;
      gl_lds16(A + (size_t)(m0 + row) * K + k0 + sc, (char*)As + c * 1024);
      gl_lds16(Bt + (size_t)(n0 + row) * K + k0 + sc, (char*)Bs + c * 1024);
    }
    __syncthreads();

    bf16x8 af[4], bf[4];
#pragma unroll
    for (int mi = 0; mi < 4; ++mi)
      af[mi] = *(const bf16x8*)((const char*)As + (wr * 64 + mi * 16 + rl) * 64 + cpr);
#pragma unroll
    for (int ni = 0; ni < 4; ++ni)
      bf[ni] = *(const bf16x8*)((const char*)Bs + (wc * 64 + ni * 16 + rl) * 64 + cpr);
    __builtin_amdgcn_s_setprio(1);
#pragma unroll
    for (int mi = 0; mi < 4; ++mi)
#pragma unroll
      for (int ni = 0; ni < 4; ++ni)
        acc[mi][ni] = MFMA16(af[mi], bf[ni], acc[mi][ni]);
    __builtin_amdgcn_s_setprio(0);
  }

#pragma unroll
  for (int mi = 0; mi < 4; ++mi) {
#pragma unroll
    for (int ni = 0; ni < 4; ++ni) {
      const int row = m0 + wr * 64 + mi * 16 + ((lane >> 4) << 2);
      const int col = n0 + wc * 64 + ni * 16 + (lane & 15);
#pragma unroll
      for (int j = 0; j < 4; ++j) {
        if (FINAL) {
          reinterpret_cast<float*>(Cout)[(size_t)(row + j) * N + col] =
              acc[mi][ni][j] + bias[col];
        } else {
          reinterpret_cast<u16*>(Cout)[(size_t)(row + j) * N + col] =
              f32_to_bf16_rne(acc[mi][ni][j]);
        }
      }
    }
  }
}

// ---------------------------------------------------------------- attention
// scores[t,s] = (k_t . q_s)/8, causal, softmax over s, O = P @ V.
// Round-6 inner structure UNCHANGED (QK transposed 32x32x16, lane-local no-max
// softmax, reg-resident P, Ks-alias 32KB LDS). NEW: s-range SPLITTING for
// concurrency -- r6 diagnosis: occupancy was grid/lifetime-bound (avg 2.25
// blocks/CU, both pipes <35%), not resource-bound.
//   p in [0,8):  one block, s-tiles [0, 2p+2), writes xb directly (normalized)
//   p in [8,16): TWO blocks: c0 = tiles [0,p+1), c1 = [p+1,2p+2); each writes
//                unnormalized partial O (bf16) + l (f32); no-max softmax makes
//                the combine LINEAR: O=(O0+O1)/(l0+l1) in a tiny second kernel.
// 1536 blocks (was 1024), sizes 2..16 tiles (was 2..34), LPT + XCD-grouped.
#define KQVS 3072
#define SCL 0.18033688011f /* 0.125 * log2(e) */
#define NEG (-1e30f)

__device__ __forceinline__ void v_load(uint4* vr, const u16* __restrict__ Vsrc,
                                       int s0, int tid) {
#pragma unroll
  for (int it = 0; it < 2; ++it) {
    const int idx = it * 256 + tid;
    const int g = idx & 7, srow = idx >> 3;
    vr[it] = *reinterpret_cast<const uint4*>(Vsrc + (size_t)(s0 + srow) * KQVS + g * 8);
  }
}

// Vt granule layout: granule (cc = s>>3, d) at u16 offset (cc*64+d)*8, slot s&7.
__device__ __forceinline__ void vt_write(u16* buf, const uint4* vr, int tid) {
#pragma unroll
  for (int it = 0; it < 2; ++it) {
    const int idx = it * 256 + tid;
    const int g = idx & 7, srow = idx >> 3;
    const u16* pv = reinterpret_cast<const u16*>(&vr[it]);
#pragma unroll
    for (int u = 0; u < 8; ++u) {
      const int ue = (u + g) & 7;  // per-lane rotation: conflict-free banks
      const int d = g * 8 + ue;
      buf[((srow >> 3) * 64 + d) * 8 + (srow & 7)] = pv[ue];
    }
  }
}

__global__ __launch_bounds__(256, 3) void attn_kernel(
    const u16* __restrict__ KQV, u16* __restrict__ Ob,
    u16* __restrict__ pOb, float* __restrict__ pLb) {
  // layout: [0,8K)=Q0  [8K,16K)=V0  [16K,24K)=Q1  [24K,32K)=V1
  // Ks (prologue only) aliases [16K,32K).
  __shared__ __attribute__((aligned(16))) char smem[32768];

  const int tid = threadIdx.x;
  const int lane = tid & 63;
  const int wv = tid >> 6;
  const int l31 = lane & 31;
  const int hh = lane >> 5;
  const bool lolane = (hh == 0);

  // 1536 blocks = 8 XCD x 192; within XCD: 8 bh x 24 chunks (LPT order).
  const int idx = blockIdx.x;
  const int virt = (idx & 7) * 192 + (idx >> 3);
  const int bh = virt / 24;
  const int u = virt - bh * 24;
  // chunk decode: u<16 -> split halves of p=15-(u>>1); u>=16 -> whole p=23-u
  int p, c, stb, ste;
  if (u < 16) {
    p = 15 - (u >> 1);
    c = u & 1;
    stb = c ? (p + 1) : 0;
    ste = c ? (2 * p + 2) : (p + 1);
  } else {
    p = 23 - u;
    c = 0;
    stb = 0;
    ste = 2 * p + 2;
  }
  const bool split = (u < 16);
  const int b = bh >> 4, head = bh & 15;

  const size_t rbase = (size_t)b * 2048;
  const u16* Kh = KQV + rbase * KQVS + head * 64;
  const u16* Qh = Kh + 1024;
  const u16* Vh = Kh + 2048;
  u16* Oh = Ob + rbase * 1024 + head * 64;

  const int t0 = p * 128;
  const int nloc = ste - stb;
  const int t0w = t0 + wv * 32;
  const int tl = t0w + l31;
  const int rb4 = 4 * hh;

  // ---- prologue: stage K (16 chunks -> [16K,32K)), Q@stb, V@stb
#pragma unroll
  for (int i = 0; i < 4; ++i) {
    const int ch = wv * 4 + i;
    const int cc = ch >> 1;
    const int trow = (ch & 1) * 64 + lane;
    gl_lds16(Kh + (size_t)(t0 + trow) * KQVS + cc * 8, smem + 16384 + ch * 1024);
  }
#pragma unroll
  for (int i = 0; i < 2; ++i) {
    const int ch = wv * 2 + i;
    gl_lds16(Qh + (size_t)(stb * 64 + lane) * KQVS + ch * 8, smem + ch * 1024);
  }
  {
    uint4 vr0[2];
    v_load(vr0, Vh, stb * 64, tid);
    vt_write((u16*)(smem + 8192), vr0, tid);
  }
  __syncthreads();

  // hoisted K fragments; Ks region is dead afterwards
  bf16x8 kf[4];
  {
    const u16* Ksp = (const u16*)(smem + 16384);
#pragma unroll
    for (int kk = 0; kk < 4; ++kk)
      kf[kk] = *(const bf16x8*)(Ksp + ((kk * 2 + hh) * 128 + wv * 32 + l31) * 8);
  }
  __syncthreads();  // protect alias: j=0 prefetch writes [16K,32K)

  f32x16 oa0 = {}, oa1 = {};
  float l_run = 0.f;

#pragma unroll 1
  for (int j = 0; j < nloc; ++j) {
    const int st = stb + j;
    const int cur = j & 1;
    const int s0 = st * 64;
    const bool pref = (j + 1 < nloc);
    uint4 vr[2];
    if (pref) {
#pragma unroll
      for (int i = 0; i < 2; ++i) {
        const int ch = wv * 2 + i;
        gl_lds16(Qh + (size_t)(s0 + 64 + lane) * KQVS + ch * 8,
                 smem + (cur ^ 1) * 16384 + ch * 1024);
      }
      v_load(vr, Vh, s0 + 64, tid);
    }

    const bool active = (s0 <= t0w + 31);
    f32x16 sa0 = {}, sa1 = {};
    if (active) {
      // ---- QK^T (transposed): C'[s,t], A = Q rows, B = hoisted K
      const u16* qb = (const u16*)(smem + cur * 16384);
      __builtin_amdgcn_s_setprio(1);
#pragma unroll
      for (int kk = 0; kk < 4; ++kk) {
        bf16x8 a0 = *(const bf16x8*)(qb + ((kk * 2 + hh) * 64 + l31) * 8);
        bf16x8 a1 = *(const bf16x8*)(qb + ((kk * 2 + hh) * 64 + 32 + l31) * 8);
        sa0 = MFMA32(a0, kf[kk], sa0);
        sa1 = MFMA32(a1, kf[kk], sa1);
      }
      __builtin_amdgcn_s_setprio(0);

      // ---- causal mask (near-diagonal tiles only)
      if (s0 + 63 > t0w) {
#pragma unroll
        for (int r = 0; r < 16; ++r) {
          const int rowloc = (r & 3) + 8 * (r >> 2) + rb4;
          if (s0 + rowloc > tl) sa0[r] = NEG;
          if (s0 + 32 + rowloc > tl) sa1[r] = NEG;
        }
      }

      // ---- P = exp2(S*SCL) (no max subtraction), row-sum
#pragma unroll
      for (int r = 0; r < 16; ++r) {
        sa0[r] = fast_exp2(sa0[r] * SCL);
        sa1[r] = fast_exp2(sa1[r] * SCL);
      }
      float rsA = ((sa0[0] + sa0[1]) + (sa0[2] + sa0[3])) +
                  ((sa0[4] + sa0[5]) + (sa0[6] + sa0[7]));
      float rsB = ((sa0[8] + sa0[9]) + (sa0[10] + sa0[11])) +
                  ((sa0[12] + sa0[13]) + (sa0[14] + sa0[15]));
      float rsC = ((sa1[0] + sa1[1]) + (sa1[2] + sa1[3])) +
                  ((sa1[4] + sa1[5]) + (sa1[6] + sa1[7]));
      float rsD = ((sa1[8] + sa1[9]) + (sa1[10] + sa1[11])) +
                  ((sa1[12] + sa1[13]) + (sa1[14] + sa1[15]));
      float rs = (rsA + rsB) + (rsC + rsD);
      rs += __shfl_xor(rs, 32);
      l_run += rs;
    }

    // ---- write NEXT V tile (loads were issued before QK)
    if (pref) vt_write((u16*)(smem + (cur ^ 1) * 16384 + 8192), vr, tid);

    // ---- O += P @ V : A-frag assembled in-register from P
    if (active) {
      const u16* vb = (const u16*)(smem + cur * 16384 + 8192);
      __builtin_amdgcn_s_setprio(1);
#define PV_WINDOW(P, r0, w)                                                   \
  {                                                                           \
    uint32_t dA = cvt_pk_bf16(P[r0 + 0], P[r0 + 1]);                          \
    uint32_t dB = cvt_pk_bf16(P[r0 + 2], P[r0 + 3]);                          \
    uint32_t dC = cvt_pk_bf16(P[r0 + 4], P[r0 + 5]);                          \
    uint32_t dD = cvt_pk_bf16(P[r0 + 6], P[r0 + 7]);                          \
    uint32_t sdA = (uint32_t)__shfl_xor((int)dA, 32);                         \
    uint32_t sdB = (uint32_t)__shfl_xor((int)dB, 32);                         \
    uint32_t sdC = (uint32_t)__shfl_xor((int)dC, 32);                         \
    uint32_t sdD = (uint32_t)__shfl_xor((int)dD, 32);                         \
    union { uint32_t u[4]; bf16x8 v; } af;                                    \
    af.u[0] = lolane ? dA : sdC;                                              \
    af.u[1] = lolane ? dB : sdD;                                              \
    af.u[2] = lolane ? sdA : dC;                                              \
    af.u[3] = lolane ? sdB : dD;                                              \
    bf16x8 bv0 = *(const bf16x8*)(vb + ((2 * (w) + hh) * 64 + l31) * 8);      \
    bf16x8 bv1 = *(const bf16x8*)(vb + ((2 * (w) + hh) * 64 + 32 + l31) * 8); \
    oa0 = MFMA32(af.v, bv0, oa0);                                             \
    oa1 = MFMA32(af.v, bv1, oa1);                                             \
  }
      PV_WINDOW(sa0, 0, 0)
      PV_WINDOW(sa0, 8, 1)
      PV_WINDOW(sa1, 0, 2)
      PV_WINDOW(sa1, 8, 3)
#undef PV_WINDOW
      __builtin_amdgcn_s_setprio(0);
    }
    __syncthreads();
  }

  // ---- epilogue
  if (!split) {
    const float inv = 1.0f / l_run;
#pragma unroll
    for (int r = 0; r < 16; ++r) {
      const int rowloc = (r & 3) + 8 * (r >> 2) + rb4;
      const float ir = __shfl(inv, rowloc);
      const int trow = t0w + rowloc;
      Oh[(size_t)trow * 1024 + l31] = f32_to_bf16_rne(oa0[r] * ir);
      Oh[(size_t)trow * 1024 + 32 + l31] = f32_to_bf16_rne(oa1[r] * ir);
    }
  } else {
    const int pidx = (bh * 8 + (p - 8)) * 2 + c;
    u16* po = pOb + (size_t)pidx * 8192;
    float* pl = pLb + pidx * 128;
    if (hh == 0) pl[wv * 32 + l31] = l_run;
#pragma unroll
    for (int r = 0; r < 16; ++r) {
      const int rowloc = (r & 3) + 8 * (r >> 2) + rb4;
      const int row = wv * 32 + rowloc;
      po[row * 64 + l31] = f32_to_bf16_rne(oa0[r]);
      po[row * 64 + 32 + l31] = f32_to_bf16_rne(oa1[r]);
    }
  }
}

// ---------------------------------------------------------------- combine
// O = (O0 + O1) / (l0 + l1) for split tiles p=8..15. 512 blocks x 256 thr.
__global__ void attn_combine_kernel(const u16* __restrict__ pOb,
                                    const float* __restrict__ pLb,
                                    u16* __restrict__ Ob) {
  const int blk = blockIdx.x;
  const int bh = blk >> 3, pi = blk & 7;
  const int p = pi + 8;
  const int b = bh >> 4, head = bh & 15;
  const int base = (bh * 8 + pi) * 2;
  const u16* po0 = pOb + (size_t)base * 8192;
  const u16* po1 = po0 + 8192;
  const float* pl0 = pLb + base * 128;
  const float* pl1 = pl0 + 128;
  u16* Oh = Ob + ((size_t)b * 2048 + p * 128) * 1024 + head * 64;

  const int tid = threadIdx.x;
  const int rr = tid >> 3;
  const int cc = (tid & 7) * 8;
#pragma unroll
  for (int g = 0; g < 4; ++g) {
    const int row = g * 32 + rr;
    const float inv = 1.0f / (pl0[row] + pl1[row]);
    uint4 a = *(const uint4*)(po0 + row * 64 + cc);
    uint4 bb = *(const uint4*)(po1 + row * 64 + cc);
    const u16* pa = (const u16*)&a;
    const u16* pb = (const u16*)&bb;
    u16 out[8];
#pragma unroll
    for (int e = 0; e < 8; ++e)
      out[e] = f32_to_bf16_rne((bf16_to_f32(pa[e]) + bf16_to_f32(pb[e])) * inv);
    *(uint4*)(Oh + (size_t)row * 1024 + cc) = *(const uint4*)out;
  }
}

// ---------------------------------------------------------------- launch
extern "C" void kernel_launch(void* const* d_in, const int* in_sizes, int n_in,
                              void* d_out, int out_size, void* d_ws, size_t ws_size,
                              hipStream_t stream) {
  (void)in_sizes; (void)n_in; (void)out_size; (void)ws_size;
  const float* x  = (const float*)d_in[0];
  const float* Wk = (const float*)d_in[1];
  const float* Wq = (const float*)d_in[2];
  const float* Wv = (const float*)d_in[3];
  const float* Wo = (const float*)d_in[4];
  const float* bo = (const float*)d_in[5];
  float* out = (float*)d_out;

  char* ws = (char*)d_ws;
  u16* xb   = (u16*)(ws);                       // 16MB (x cast, later attn-out)
  u16* kqv  = (u16*)(ws + ((size_t)16 << 20));  // 48MB [8192 x 3072] K|Q|V
  u16* wqkv = (u16*)(ws + ((size_t)64 << 20));  // 6MB  [3072 x 1024]
  u16* wob  = (u16*)(ws + ((size_t)70 << 20));  // 2MB
  u16* pOb  = (u16*)(ws + ((size_t)72 << 20));  // 16MB partial O (1024 x 8192 bf16)
  float* pLb = (float*)(ws + ((size_t)88 << 20)); // 512KB partial l -> 88.5MB total

  cast_all_kernel<<<dim3(12288), 256, 0, stream>>>(x, Wk, Wq, Wv, Wo, xb, wqkv, wob);

  // fused K/Q/V projection: [8192,3072] = [8192,1024] x [3072,1024]^T
  gemm_bt_kernel<0><<<dim3(24, 64), 256, 0, stream>>>(xb, wqkv, kqv, nullptr, 8192, 3072, 1024);

  // attention (split-s flash: whole tiles write xb; split tiles write partials)
  attn_kernel<<<dim3(1536), 256, 0, stream>>>(kqv, xb, pOb, pLb);
  attn_combine_kernel<<<dim3(512), 256, 0, stream>>>(pOb, pLb, xb);

  // final projection + bias, f32 out
  gemm_bt_kernel<1><<<dim3(8, 64), 256, 0, stream>>>(xb, wob, out, bo, 8192, 1024, 1024);
}

// Round 8
// 190.890 us; speedup vs baseline: 1.1398x; 1.1398x over previous
//
#include <hip/hip_runtime.h>
#include <hip/hip_bf16.h>
#include <stdint.h>

typedef __attribute__((ext_vector_type(8))) __bf16 bf16x8;
typedef __attribute__((ext_vector_type(4))) float f32x4;
typedef __attribute__((ext_vector_type(16))) float f32x16;
typedef unsigned short u16;

#define MFMA16(a, b, c) __builtin_amdgcn_mfma_f32_16x16x32_bf16((a), (b), (c), 0, 0, 0)
#define MFMA32(a, b, c) __builtin_amdgcn_mfma_f32_32x32x16_bf16((a), (b), (c), 0, 0, 0)

__device__ __forceinline__ u16 f32_to_bf16_rne(float f) {
  union { float f; uint32_t u; } v; v.f = f;
  uint32_t u = v.u;
  u += 0x7fffu + ((u >> 16) & 1u);
  return (u16)(u >> 16);
}

__device__ __forceinline__ void gl_lds16(const void* g, void* l) {
  __builtin_amdgcn_global_load_lds(
      (const __attribute__((address_space(1))) void*)(uintptr_t)g,
      (__attribute__((address_space(3))) void*)(uintptr_t)l,
      16, 0, 0);
}

__device__ __forceinline__ float fast_exp2(float x) {
#if __has_builtin(__builtin_amdgcn_exp2f)
  return __builtin_amdgcn_exp2f(x);
#else
  return exp2f(x);
#endif
}

__device__ __forceinline__ uint32_t cvt_pk_bf16(float a, float b) {
  uint32_t r;
  asm("v_cvt_pk_bf16_f32 %0, %1, %2" : "=v"(r) : "v"(a), "v"(b));
  return r;
}

// ---------------------------------------------------------------- fused cast
__global__ void cast_all_kernel(const float* __restrict__ x, const float* __restrict__ Wk,
                                const float* __restrict__ Wq, const float* __restrict__ Wv,
                                const float* __restrict__ Wo, u16* __restrict__ xb,
                                u16* __restrict__ wqkv, u16* __restrict__ wob) {
  const int i = blockIdx.x * 256 + threadIdx.x;
  const float* src; u16* dst; int off;
  if (i < 2097152)      { src = x;  dst = xb;             off = i; }
  else if (i < 2359296) { src = Wk; dst = wqkv;           off = i - 2097152; }
  else if (i < 2621440) { src = Wq; dst = wqkv + 1048576; off = i - 2359296; }
  else if (i < 2883584) { src = Wv; dst = wqkv + 2097152; off = i - 2621440; }
  else                  { src = Wo; dst = wob;            off = i - 2883584; }
  float4 v = reinterpret_cast<const float4*>(src)[off];
  ushort4 o;
  o.x = f32_to_bf16_rne(v.x);
  o.y = f32_to_bf16_rne(v.y);
  o.z = f32_to_bf16_rne(v.z);
  o.w = f32_to_bf16_rne(v.w);
  reinterpret_cast<ushort4*>(dst)[off] = o;
}

// ---------------------------------------------------------------- GEMM (B^T)
// C[m,n] = sum_k A[m,k]*Bt[n,k]. 128x128 tile, BK=32, 4 waves (2x2), 4x4 frags.
template <int FINAL>
__global__ __launch_bounds__(256, 2) void gemm_bt_kernel(
    const u16* __restrict__ A, const u16* __restrict__ Bt,
    void* __restrict__ Cout, const float* __restrict__ bias, int M, int N, int K) {
  __shared__ __attribute__((aligned(16))) u16 As[128 * 32];
  __shared__ __attribute__((aligned(16))) u16 Bs[128 * 32];
  const int tid = threadIdx.x;
  const int lane = tid & 63;
  const int wid = tid >> 6;
  const int wr = wid >> 1, wc = wid & 1;
  const int m0 = blockIdx.y * 128, n0 = blockIdx.x * 128;

  f32x4 acc[4][4] = {};

  const int sr = lane >> 2;
  const int scc = lane & 3;
  const int sh = (sr ^ (sr >> 2)) & 3;
  const int sc = ((scc ^ sh) << 3);
  const int rl = lane & 15;
  const int rh = (rl ^ (rl >> 2)) & 3;
  const int cpr = (((lane >> 4) ^ rh) << 4);

  for (int k0 = 0; k0 < K; k0 += 32) {
    __syncthreads();
#pragma unroll
    for (int i = 0; i < 2; ++i) {
      const int c = wid * 2 + i;
      const int row = c * 16 + sr;
      gl_lds16(A + (size_t)(m0 + row) * K + k0 + sc, (char*)As + c * 1024);
      gl_lds16(Bt + (size_t)(n0 + row) * K + k0 + sc, (char*)Bs + c * 1024);
    }
    __syncthreads();

    bf16x8 af[4], bf[4];
#pragma unroll
    for (int mi = 0; mi < 4; ++mi)
      af[mi] = *(const bf16x8*)((const char*)As + (wr * 64 + mi * 16 + rl) * 64 + cpr);
#pragma unroll
    for (int ni = 0; ni < 4; ++ni)
      bf[ni] = *(const bf16x8*)((const char*)Bs + (wc * 64 + ni * 16 + rl) * 64 + cpr);
    __builtin_amdgcn_s_setprio(1);
#pragma unroll
    for (int mi = 0; mi < 4; ++mi)
#pragma unroll
      for (int ni = 0; ni < 4; ++ni)
        acc[mi][ni] = MFMA16(af[mi], bf[ni], acc[mi][ni]);
    __builtin_amdgcn_s_setprio(0);
  }

#pragma unroll
  for (int mi = 0; mi < 4; ++mi) {
#pragma unroll
    for (int ni = 0; ni < 4; ++ni) {
      const int row = m0 + wr * 64 + mi * 16 + ((lane >> 4) << 2);
      const int col = n0 + wc * 64 + ni * 16 + (lane & 15);
#pragma unroll
      for (int j = 0; j < 4; ++j) {
        if (FINAL) {
          reinterpret_cast<float*>(Cout)[(size_t)(row + j) * N + col] =
              acc[mi][ni][j] + bias[col];
        } else {
          reinterpret_cast<u16*>(Cout)[(size_t)(row + j) * N + col] =
              f32_to_bf16_rne(acc[mi][ni][j]);
        }
      }
    }
  }
}

// ---------------------------------------------------------------- attention
// scores[t,s] = (k_t . q_s)/8, causal, softmax over s, O = P @ V.
// Round-6 structure (94.6us proven; split-s of r7 REVERTED) + counted-vmcnt
// pipelining (T3/T4): the per-iteration __syncthreads used to drain vmcnt(0),
// exposing the Q global_load_lds HBM latency every s-tile. Now:
//   - issue V reg-loads BEFORE Q gl_lds (so the compiler's wait for V leaves
//     the Q prefetch in flight: vmcnt(2)),
//   - explicit s_waitcnt vmcnt(4) before the QK ds_reads (waits only Q_cur;
//     queue = [Q_cur(2), V_next(2), Q_next(2)]), vmcnt(0) on the last iter,
//   - end-of-iter: s_waitcnt lgkmcnt(0) + RAW s_barrier (no vmem drain).
// Race analysis: the barrier rendezvous still orders all cross-wave LDS
// reuse (gl_lds writes land after issue, issues happen after the barrier);
// read-after-gl_lds is guarded by the counted vmcnt.
#define KQVS 3072
#define SCL 0.18033688011f /* 0.125 * log2(e) */
#define NEG (-1e30f)

__device__ __forceinline__ void v_load(uint4* vr, const u16* __restrict__ Vsrc,
                                       int s0, int tid) {
#pragma unroll
  for (int it = 0; it < 2; ++it) {
    const int idx = it * 256 + tid;
    const int g = idx & 7, srow = idx >> 3;
    vr[it] = *reinterpret_cast<const uint4*>(Vsrc + (size_t)(s0 + srow) * KQVS + g * 8);
  }
}

// Vt granule layout: granule (cc = s>>3, d) at u16 offset (cc*64+d)*8, slot s&7.
__device__ __forceinline__ void vt_write(u16* buf, const uint4* vr, int tid) {
#pragma unroll
  for (int it = 0; it < 2; ++it) {
    const int idx = it * 256 + tid;
    const int g = idx & 7, srow = idx >> 3;
    const u16* pv = reinterpret_cast<const u16*>(&vr[it]);
#pragma unroll
    for (int u = 0; u < 8; ++u) {
      const int ue = (u + g) & 7;  // per-lane rotation: conflict-free banks
      const int d = g * 8 + ue;
      buf[((srow >> 3) * 64 + d) * 8 + (srow & 7)] = pv[ue];
    }
  }
}

__global__ __launch_bounds__(256, 3) void attn_kernel(
    const u16* __restrict__ KQV, u16* __restrict__ Ob) {
  // layout: [0,8K)=Q0  [8K,16K)=V0  [16K,24K)=Q1  [24K,32K)=V1
  // Ks (prologue only) aliases [16K,32K).
  __shared__ __attribute__((aligned(16))) char smem[32768];

  const int tid = threadIdx.x;
  const int lane = tid & 63;
  const int wv = tid >> 6;
  const int l31 = lane & 31;
  const int hh = lane >> 5;
  const bool lolane = (hh == 0);

  // big-tiles-first (LPT) + XCD-grouped (b,h)
  const int idx = blockIdx.x;
  const int ttile = 15 - (idx >> 6);
  const int bhpos = idx & 63;
  const int bh = (bhpos & 7) * 8 + (bhpos >> 3);
  const int b = bh >> 4, head = bh & 15;

  const size_t rbase = (size_t)b * 2048;
  const u16* Kh = KQV + rbase * KQVS + head * 64;
  const u16* Qh = Kh + 1024;
  const u16* Vh = Kh + 2048;
  u16* Oh = Ob + rbase * 1024 + head * 64;

  const int t0 = ttile * 128;
  const int nst = 2 * ttile + 2;
  const int t0w = t0 + wv * 32;
  const int tl = t0w + l31;
  const int rb4 = 4 * hh;

  // ---- prologue: stage K (16 chunks -> [16K,32K)), Q0, V0
#pragma unroll
  for (int i = 0; i < 4; ++i) {
    const int ch = wv * 4 + i;
    const int cc = ch >> 1;
    const int trow = (ch & 1) * 64 + lane;
    gl_lds16(Kh + (size_t)(t0 + trow) * KQVS + cc * 8, smem + 16384 + ch * 1024);
  }
#pragma unroll
  for (int i = 0; i < 2; ++i) {
    const int ch = wv * 2 + i;
    gl_lds16(Qh + (size_t)lane * KQVS + ch * 8, smem + ch * 1024);
  }
  {
    uint4 vr0[2];
    v_load(vr0, Vh, 0, tid);
    vt_write((u16*)(smem + 8192), vr0, tid);
  }
  __syncthreads();

  // hoisted K fragments; Ks region is dead afterwards
  bf16x8 kf[4];
  {
    const u16* Ksp = (const u16*)(smem + 16384);
#pragma unroll
    for (int kk = 0; kk < 4; ++kk)
      kf[kk] = *(const bf16x8*)(Ksp + ((kk * 2 + hh) * 128 + wv * 32 + l31) * 8);
  }
  __syncthreads();  // protect alias: st=0 prefetch writes [16K,32K)

  f32x16 oa0 = {}, oa1 = {};
  float l_run = 0.f;

#pragma unroll 1
  for (int st = 0; st < nst; ++st) {
    const int cur = st & 1;
    const int s0 = st * 64;
    const bool pref = (st + 1 < nst);
    uint4 vr[2];
    if (pref) {
      // V FIRST (reg loads), then Q gl_lds: vt_write's compiler-inserted wait
      // becomes vmcnt(2), leaving the Q prefetch in flight across the barrier.
      v_load(vr, Vh, s0 + 64, tid);
#pragma unroll
      for (int i = 0; i < 2; ++i) {
        const int ch = wv * 2 + i;
        gl_lds16(Qh + (size_t)(s0 + 64 + lane) * KQVS + ch * 8,
                 smem + (cur ^ 1) * 16384 + ch * 1024);
      }
    }

    const bool active = (s0 <= t0w + 31);  // wave-uniform
    f32x16 sa0 = {}, sa1 = {};
    if (active) {
      // wait ONLY Q_cur: queue = [Q_cur(2), V_next(2), Q_next(2)]
      if (pref) {
        asm volatile("s_waitcnt vmcnt(4)" ::: "memory");
      } else {
        asm volatile("s_waitcnt vmcnt(0)" ::: "memory");
      }
      __builtin_amdgcn_sched_barrier(0);

      // ---- QK^T (transposed): C'[s,t], A = Q rows, B = hoisted K
      const u16* qb = (const u16*)(smem + cur * 16384);
      __builtin_amdgcn_s_setprio(1);
#pragma unroll
      for (int kk = 0; kk < 4; ++kk) {
        bf16x8 a0 = *(const bf16x8*)(qb + ((kk * 2 + hh) * 64 + l31) * 8);
        bf16x8 a1 = *(const bf16x8*)(qb + ((kk * 2 + hh) * 64 + 32 + l31) * 8);
        sa0 = MFMA32(a0, kf[kk], sa0);
        sa1 = MFMA32(a1, kf[kk], sa1);
      }
      __builtin_amdgcn_s_setprio(0);

      // ---- causal mask (near-diagonal tiles only)
      if (s0 + 63 > t0w) {
#pragma unroll
        for (int r = 0; r < 16; ++r) {
          const int rowloc = (r & 3) + 8 * (r >> 2) + rb4;
          if (s0 + rowloc > tl) sa0[r] = NEG;
          if (s0 + 32 + rowloc > tl) sa1[r] = NEG;
        }
      }

      // ---- P = exp2(S*SCL) (no max subtraction), row-sum
#pragma unroll
      for (int r = 0; r < 16; ++r) {
        sa0[r] = fast_exp2(sa0[r] * SCL);
        sa1[r] = fast_exp2(sa1[r] * SCL);
      }
      float rsA = ((sa0[0] + sa0[1]) + (sa0[2] + sa0[3])) +
                  ((sa0[4] + sa0[5]) + (sa0[6] + sa0[7]));
      float rsB = ((sa0[8] + sa0[9]) + (sa0[10] + sa0[11])) +
                  ((sa0[12] + sa0[13]) + (sa0[14] + sa0[15]));
      float rsC = ((sa1[0] + sa1[1]) + (sa1[2] + sa1[3])) +
                  ((sa1[4] + sa1[5]) + (sa1[6] + sa1[7]));
      float rsD = ((sa1[8] + sa1[9]) + (sa1[10] + sa1[11])) +
                  ((sa1[12] + sa1[13]) + (sa1[14] + sa1[15]));
      float rs = (rsA + rsB) + (rsC + rsD);
      rs += __shfl_xor(rs, 32);
      l_run += rs;
    }

    // ---- write NEXT V tile (compiler waits vr -> vmcnt(2), Q stays in flight)
    if (pref) vt_write((u16*)(smem + (cur ^ 1) * 16384 + 8192), vr, tid);

    // ---- O += P @ V : A-frag assembled in-register from P
    if (active) {
      const u16* vb = (const u16*)(smem + cur * 16384 + 8192);
      __builtin_amdgcn_s_setprio(1);
#define PV_WINDOW(P, r0, w)                                                   \
  {                                                                           \
    uint32_t dA = cvt_pk_bf16(P[r0 + 0], P[r0 + 1]);                          \
    uint32_t dB = cvt_pk_bf16(P[r0 + 2], P[r0 + 3]);                          \
    uint32_t dC = cvt_pk_bf16(P[r0 + 4], P[r0 + 5]);                          \
    uint32_t dD = cvt_pk_bf16(P[r0 + 6], P[r0 + 7]);                          \
    uint32_t sdA = (uint32_t)__shfl_xor((int)dA, 32);                         \
    uint32_t sdB = (uint32_t)__shfl_xor((int)dB, 32);                         \
    uint32_t sdC = (uint32_t)__shfl_xor((int)dC, 32);                         \
    uint32_t sdD = (uint32_t)__shfl_xor((int)dD, 32);                         \
    union { uint32_t u[4]; bf16x8 v; } af;                                    \
    af.u[0] = lolane ? dA : sdC;                                              \
    af.u[1] = lolane ? dB : sdD;                                              \
    af.u[2] = lolane ? sdA : dC;                                              \
    af.u[3] = lolane ? sdB : dD;                                              \
    bf16x8 bv0 = *(const bf16x8*)(vb + ((2 * (w) + hh) * 64 + l31) * 8);      \
    bf16x8 bv1 = *(const bf16x8*)(vb + ((2 * (w) + hh) * 64 + 32 + l31) * 8); \
    oa0 = MFMA32(af.v, bv0, oa0);                                             \
    oa1 = MFMA32(af.v, bv1, oa1);                                             \
  }
      PV_WINDOW(sa0, 0, 0)
      PV_WINDOW(sa0, 8, 1)
      PV_WINDOW(sa1, 0, 2)
      PV_WINDOW(sa1, 8, 3)
#undef PV_WINDOW
      __builtin_amdgcn_s_setprio(0);
    }

    // raw barrier: LDS writes made visible; global prefetch NOT drained.
    asm volatile("s_waitcnt lgkmcnt(0)" ::: "memory");
    __builtin_amdgcn_s_barrier();
  }

  // ---- epilogue: normalize (1/l broadcast P-domain -> O-domain), store
  {
    const float inv = 1.0f / l_run;
#pragma unroll
    for (int r = 0; r < 16; ++r) {
      const int rowloc = (r & 3) + 8 * (r >> 2) + rb4;
      const float ir = __shfl(inv, rowloc);
      const int trow = t0w + rowloc;
      Oh[(size_t)trow * 1024 + l31] = f32_to_bf16_rne(oa0[r] * ir);
      Oh[(size_t)trow * 1024 + 32 + l31] = f32_to_bf16_rne(oa1[r] * ir);
    }
  }
}

// ---------------------------------------------------------------- launch
extern "C" void kernel_launch(void* const* d_in, const int* in_sizes, int n_in,
                              void* d_out, int out_size, void* d_ws, size_t ws_size,
                              hipStream_t stream) {
  (void)in_sizes; (void)n_in; (void)out_size; (void)ws_size;
  const float* x  = (const float*)d_in[0];
  const float* Wk = (const float*)d_in[1];
  const float* Wq = (const float*)d_in[2];
  const float* Wv = (const float*)d_in[3];
  const float* Wo = (const float*)d_in[4];
  const float* bo = (const float*)d_in[5];
  float* out = (float*)d_out;

  char* ws = (char*)d_ws;
  u16* xb   = (u16*)(ws);                       // 16MB (x cast, later attn-out)
  u16* kqv  = (u16*)(ws + ((size_t)16 << 20));  // 48MB [8192 x 3072] K|Q|V
  u16* wqkv = (u16*)(ws + ((size_t)64 << 20));  // 6MB  [3072 x 1024]
  u16* wob  = (u16*)(ws + ((size_t)70 << 20));  // 2MB -> 72MB total

  cast_all_kernel<<<dim3(12288), 256, 0, stream>>>(x, Wk, Wq, Wv, Wo, xb, wqkv, wob);

  // fused K/Q/V projection: [8192,3072] = [8192,1024] x [3072,1024]^T
  gemm_bt_kernel<0><<<dim3(24, 64), 256, 0, stream>>>(xb, wqkv, kqv, nullptr, 8192, 3072, 1024);

  // attention (writes into xb)
  attn_kernel<<<dim3(1024), 256, 0, stream>>>(kqv, xb);

  // final projection + bias, f32 out
  gemm_bt_kernel<1><<<dim3(8, 64), 256, 0, stream>>>(xb, wob, out, bo, 8192, 1024, 1024);
}

// Round 11
// 186.276 us; speedup vs baseline: 1.1680x; 1.0248x over previous
//
#include <hip/hip_runtime.h>
#include <hip/hip_bf16.h>
#include <stdint.h>

typedef __attribute__((ext_vector_type(8))) __bf16 bf16x8;
typedef __attribute__((ext_vector_type(4))) float f32x4;
typedef __attribute__((ext_vector_type(16))) float f32x16;
typedef unsigned short u16;

#define MFMA16(a, b, c) __builtin_amdgcn_mfma_f32_16x16x32_bf16((a), (b), (c), 0, 0, 0)
#define MFMA32(a, b, c) __builtin_amdgcn_mfma_f32_32x32x16_bf16((a), (b), (c), 0, 0, 0)

__device__ __forceinline__ u16 f32_to_bf16_rne(float f) {
  union { float f; uint32_t u; } v; v.f = f;
  uint32_t u = v.u;
  u += 0x7fffu + ((u >> 16) & 1u);
  return (u16)(u >> 16);
}

__device__ __forceinline__ void gl_lds16(const void* g, void* l) {
  __builtin_amdgcn_global_load_lds(
      (const __attribute__((address_space(1))) void*)(uintptr_t)g,
      (__attribute__((address_space(3))) void*)(uintptr_t)l,
      16, 0, 0);
}

__device__ __forceinline__ float fast_exp2(float x) {
#if __has_builtin(__builtin_amdgcn_exp2f)
  return __builtin_amdgcn_exp2f(x);
#else
  return exp2f(x);
#endif
}

__device__ __forceinline__ uint32_t cvt_pk_bf16(float a, float b) {
  uint32_t r;
  asm("v_cvt_pk_bf16_f32 %0, %1, %2" : "=v"(r) : "v"(a), "v"(b));
  return r;
}

// ---------------------------------------------------------------- fused cast
__global__ void cast_all_kernel(const float* __restrict__ x, const float* __restrict__ Wk,
                                const float* __restrict__ Wq, const float* __restrict__ Wv,
                                const float* __restrict__ Wo, u16* __restrict__ xb,
                                u16* __restrict__ wqkv, u16* __restrict__ wob) {
  const int i = blockIdx.x * 256 + threadIdx.x;
  const float* src; u16* dst; int off;
  if (i < 2097152)      { src = x;  dst = xb;             off = i; }
  else if (i < 2359296) { src = Wk; dst = wqkv;           off = i - 2097152; }
  else if (i < 2621440) { src = Wq; dst = wqkv + 1048576; off = i - 2359296; }
  else if (i < 2883584) { src = Wv; dst = wqkv + 2097152; off = i - 2621440; }
  else                  { src = Wo; dst = wob;            off = i - 2883584; }
  float4 v = reinterpret_cast<const float4*>(src)[off];
  ushort4 o;
  o.x = f32_to_bf16_rne(v.x);
  o.y = f32_to_bf16_rne(v.y);
  o.z = f32_to_bf16_rne(v.z);
  o.w = f32_to_bf16_rne(v.w);
  reinterpret_cast<ushort4*>(dst)[off] = o;
}

// ---------------------------------------------------------------- GEMM (B^T)
// 128x128 tile m97-structure; used for the FINAL projection only.
template <int FINAL>
__global__ __launch_bounds__(256, 2) void gemm_bt_kernel(
    const u16* __restrict__ A, const u16* __restrict__ Bt,
    void* __restrict__ Cout, const float* __restrict__ bias, int M, int N, int K) {
  __shared__ __attribute__((aligned(16))) u16 As[128 * 32];
  __shared__ __attribute__((aligned(16))) u16 Bs[128 * 32];
  const int tid = threadIdx.x;
  const int lane = tid & 63;
  const int wid = tid >> 6;
  const int wr = wid >> 1, wc = wid & 1;
  const int m0 = blockIdx.y * 128, n0 = blockIdx.x * 128;

  f32x4 acc[4][4] = {};

  const int sr = lane >> 2;
  const int scc = lane & 3;
  const int sh = (sr ^ (sr >> 2)) & 3;
  const int sc = ((scc ^ sh) << 3);
  const int rl = lane & 15;
  const int rh = (rl ^ (rl >> 2)) & 3;
  const int cpr = (((lane >> 4) ^ rh) << 4);

  for (int k0 = 0; k0 < K; k0 += 32) {
    __syncthreads();
#pragma unroll
    for (int i = 0; i < 2; ++i) {
      const int c = wid * 2 + i;
      const int row = c * 16 + sr;
      gl_lds16(A + (size_t)(m0 + row) * K + k0 + sc, (char*)As + c * 1024);
      gl_lds16(Bt + (size_t)(n0 + row) * K + k0 + sc, (char*)Bs + c * 1024);
    }
    __syncthreads();

    bf16x8 af[4], bf[4];
#pragma unroll
    for (int mi = 0; mi < 4; ++mi)
      af[mi] = *(const bf16x8*)((const char*)As + (wr * 64 + mi * 16 + rl) * 64 + cpr);
#pragma unroll
    for (int ni = 0; ni < 4; ++ni)
      bf[ni] = *(const bf16x8*)((const char*)Bs + (wc * 64 + ni * 16 + rl) * 64 + cpr);
    __builtin_amdgcn_s_setprio(1);
#pragma unroll
    for (int mi = 0; mi < 4; ++mi)
#pragma unroll
      for (int ni = 0; ni < 4; ++ni)
        acc[mi][ni] = MFMA16(af[mi], bf[ni], acc[mi][ni]);
    __builtin_amdgcn_s_setprio(0);
  }

#pragma unroll
  for (int mi = 0; mi < 4; ++mi) {
#pragma unroll
    for (int ni = 0; ni < 4; ++ni) {
      const int row = m0 + wr * 64 + mi * 16 + ((lane >> 4) << 2);
      const int col = n0 + wc * 64 + ni * 16 + (lane & 15);
#pragma unroll
      for (int j = 0; j < 4; ++j) {
        if (FINAL) {
          reinterpret_cast<float*>(Cout)[(size_t)(row + j) * N + col] =
              acc[mi][ni][j] + bias[col];
        } else {
          reinterpret_cast<u16*>(Cout)[(size_t)(row + j) * N + col] =
              f32_to_bf16_rne(acc[mi][ni][j]);
        }
      }
    }
  }
}

// ---------------------------------------------------------------- GEMM 256^2 8-phase
// r11 fix: the HALF offset is applied to the LDS destination INSIDE g256_stage
// (callers pass the 32KB A-or-B region base). r9/r10's prologue passed the
// region base while the loop passed region+half*16K -- the prologue overwrote
// half0 with half1 and left half1 as stale garbage -> NaN through softmax.
// Schedule (re-audited): iter computes kt=2i in slot0 [ph1-4], kt+1 in slot1
// [ph5-8]; stages ph1:A0(kt+1)->s1 ph2:A1->s1 ph3:B0(kt+2)->s0 ph4:B1->s0
// ph5:A0(kt+2)->s0 ph6:A1->s0 ph7:B0(kt+3)->s1 ph8:B1->s1. vmcnt(4)@ph4
// retires slot1 B+A (for ph5-8); vmcnt(4)@ph8 retires slot0 B+A (next ph1-4).
// Each stage target region is dead >=2 barriers before the stage issues.
__device__ __forceinline__ void g256_stage(const u16* __restrict__ src, int b0,
                                           int half, int t, char* region, int K,
                                           int tid) {
  char* dst = region + half * 16384;  // << the r11 fix
  const int w64 = tid & ~63;          // wave-uniform thread base
  const int lane = tid & 63;
#pragma unroll
  for (int j = 0; j < 2; ++j) {
    const int gbase = j * 512 + w64;  // wave-uniform granule base
    const int gI = gbase + lane;      // this lane's granule
    const int r = gI >> 3;
    const int c = ((gI & 7) ^ (r & 7)) * 8;  // inverse swizzle, coalesced /row
    gl_lds16(src + (size_t)(b0 + half * 128 + r) * K + t * 64 + c,
             dst + gbase * 16);  // HW: lane l lands at +l*16 -> granule gI
  }
}

template <int Q, bool LOADB, int VM>
__device__ __forceinline__ void g256_phase(
    char* lds, int slot, const u16* __restrict__ A, const u16* __restrict__ Bt,
    int m0, int n0, int K, int stT, int stHalf, bool stIsB, int stSlot,
    int wm, int wn, int l15, int l4, int tid,
    bf16x8 (&bf)[2][4], f32x4 (&acc)[8][4]) {
  const char* Ab = lds + slot * 65536 + wm * 16384;
  if (LOADB) {
    const char* Bb = lds + slot * 65536 + 32768 + (wn >> 1) * 16384;
#pragma unroll
    for (int kk = 0; kk < 2; ++kk)
#pragma unroll
      for (int ni = 0; ni < 4; ++ni) {
        const int lr = (wn & 1) * 64 + ni * 16 + l15;
        bf[kk][ni] = *(const bf16x8*)(Bb + lr * 128 + (((kk * 4 + l4) ^ (lr & 7)) << 4));
      }
  }
  bf16x8 af[2][2];
#pragma unroll
  for (int mi = 0; mi < 2; ++mi)
#pragma unroll
    for (int kk = 0; kk < 2; ++kk) {
      const int lr = (Q * 2 + mi) * 16 + l15;
      af[mi][kk] = *(const bf16x8*)(Ab + lr * 128 + (((kk * 4 + l4) ^ (lr & 7)) << 4));
    }
  {
    const u16* src = stIsB ? Bt : A;
    const int b0 = stIsB ? n0 : m0;
    char* region = lds + stSlot * 65536 + (stIsB ? 32768 : 0);
    g256_stage(src, b0, stHalf, stT, region, K, tid);
  }
  if (VM == 4) asm volatile("s_waitcnt vmcnt(4)" ::: "memory");
  __builtin_amdgcn_s_barrier();
  __builtin_amdgcn_s_setprio(1);
#pragma unroll
  for (int mi = 0; mi < 2; ++mi)
#pragma unroll
    for (int ni = 0; ni < 4; ++ni)
#pragma unroll
      for (int kk = 0; kk < 2; ++kk)
        acc[Q * 2 + mi][ni] = MFMA16(af[mi][kk], bf[kk][ni], acc[Q * 2 + mi][ni]);
  __builtin_amdgcn_s_setprio(0);
  __builtin_amdgcn_s_barrier();
}

__global__ __launch_bounds__(512) void gemm256_kernel(
    const u16* __restrict__ A, const u16* __restrict__ Bt, u16* __restrict__ C,
    int M, int N, int K) {
  __shared__ __attribute__((aligned(16))) char lds[131072];

  const int tid = threadIdx.x;
  const int lane = tid & 63;
  const int w = tid >> 6;
  const int wm = w >> 2, wn = w & 3;
  const int l15 = lane & 15, l4 = lane >> 4;

  // bijective XCD swizzle (grid % 8 == 0)
  const int bid = blockIdx.x;
  const int wg = (bid & 7) * (gridDim.x >> 3) + (bid >> 3);
  const int nbx = N >> 8;
  const int by = wg / nbx, bx = wg - by * nbx;
  const int m0 = by << 8, n0 = bx << 8;

  f32x4 acc[8][4] = {};
  bf16x8 bf[2][4];

  // ---- prologue: slot0 <- tile0 (A0,A1,B0,B1); slot1 <- tile1 (B0,B1)
  g256_stage(A, m0, 0, 0, lds, K, tid);
  g256_stage(A, m0, 1, 0, lds, K, tid);
  g256_stage(Bt, n0, 0, 0, lds + 32768, K, tid);
  g256_stage(Bt, n0, 1, 0, lds + 32768, K, tid);
  g256_stage(Bt, n0, 0, 1, lds + 65536 + 32768, K, tid);
  g256_stage(Bt, n0, 1, 1, lds + 65536 + 32768, K, tid);
  asm volatile("s_waitcnt vmcnt(4)" ::: "memory");
  __builtin_amdgcn_s_barrier();

  const int KT = K >> 6;  // 16 K-tiles, 8 iterations
#pragma unroll 1
  for (int it = 0; it < (KT >> 1); ++it) {
    const int t1 = it * 2 + 1;
    int t2 = it * 2 + 2; if (t2 > KT - 1) t2 = KT - 1;
    int t3 = it * 2 + 3; if (t3 > KT - 1) t3 = KT - 1;
    g256_phase<0, true, -1>(lds, 0, A, Bt, m0, n0, K, t1, 0, false, 1, wm, wn, l15, l4, tid, bf, acc);
    g256_phase<1, false, -1>(lds, 0, A, Bt, m0, n0, K, t1, 1, false, 1, wm, wn, l15, l4, tid, bf, acc);
    g256_phase<2, false, -1>(lds, 0, A, Bt, m0, n0, K, t2, 0, true, 0, wm, wn, l15, l4, tid, bf, acc);
    g256_phase<3, false, 4>(lds, 0, A, Bt, m0, n0, K, t2, 1, true, 0, wm, wn, l15, l4, tid, bf, acc);
    g256_phase<0, true, -1>(lds, 1, A, Bt, m0, n0, K, t2, 0, false, 0, wm, wn, l15, l4, tid, bf, acc);
    g256_phase<1, false, -1>(lds, 1, A, Bt, m0, n0, K, t2, 1, false, 0, wm, wn, l15, l4, tid, bf, acc);
    g256_phase<2, false, -1>(lds, 1, A, Bt, m0, n0, K, t3, 0, true, 1, wm, wn, l15, l4, tid, bf, acc);
    g256_phase<3, false, 4>(lds, 1, A, Bt, m0, n0, K, t3, 1, true, 1, wm, wn, l15, l4, tid, bf, acc);
  }
  // drain in-flight LDS DMA before block teardown
  asm volatile("s_waitcnt vmcnt(0)" ::: "memory");

  // ---- epilogue: C write (bf16)
#pragma unroll
  for (int mi = 0; mi < 8; ++mi) {
#pragma unroll
    for (int ni = 0; ni < 4; ++ni) {
      const int row = m0 + wm * 128 + mi * 16 + l4 * 4;
      const int col = n0 + wn * 64 + ni * 16 + l15;
#pragma unroll
      for (int j = 0; j < 4; ++j)
        C[(size_t)(row + j) * N + col] = f32_to_bf16_rne(acc[mi][ni][j]);
    }
  }
}

// ---------------------------------------------------------------- attention
// (r8 version, validated at 94.7us.)
#define KQVS 3072
#define SCL 0.18033688011f /* 0.125 * log2(e) */
#define NEG (-1e30f)

__device__ __forceinline__ void v_load(uint4* vr, const u16* __restrict__ Vsrc,
                                       int s0, int tid) {
#pragma unroll
  for (int it = 0; it < 2; ++it) {
    const int idx = it * 256 + tid;
    const int g = idx & 7, srow = idx >> 3;
    vr[it] = *reinterpret_cast<const uint4*>(Vsrc + (size_t)(s0 + srow) * KQVS + g * 8);
  }
}

__device__ __forceinline__ void vt_write(u16* buf, const uint4* vr, int tid) {
#pragma unroll
  for (int it = 0; it < 2; ++it) {
    const int idx = it * 256 + tid;
    const int g = idx & 7, srow = idx >> 3;
    const u16* pv = reinterpret_cast<const u16*>(&vr[it]);
#pragma unroll
    for (int u = 0; u < 8; ++u) {
      const int ue = (u + g) & 7;
      const int d = g * 8 + ue;
      buf[((srow >> 3) * 64 + d) * 8 + (srow & 7)] = pv[ue];
    }
  }
}

__global__ __launch_bounds__(256, 3) void attn_kernel(
    const u16* __restrict__ KQV, u16* __restrict__ Ob) {
  __shared__ __attribute__((aligned(16))) char smem[32768];

  const int tid = threadIdx.x;
  const int lane = tid & 63;
  const int wv = tid >> 6;
  const int l31 = lane & 31;
  const int hh = lane >> 5;
  const bool lolane = (hh == 0);

  const int idx = blockIdx.x;
  const int ttile = 15 - (idx >> 6);
  const int bhpos = idx & 63;
  const int bh = (bhpos & 7) * 8 + (bhpos >> 3);
  const int b = bh >> 4, head = bh & 15;

  const size_t rbase = (size_t)b * 2048;
  const u16* Kh = KQV + rbase * KQVS + head * 64;
  const u16* Qh = Kh + 1024;
  const u16* Vh = Kh + 2048;
  u16* Oh = Ob + rbase * 1024 + head * 64;

  const int t0 = ttile * 128;
  const int nst = 2 * ttile + 2;
  const int t0w = t0 + wv * 32;
  const int tl = t0w + l31;
  const int rb4 = 4 * hh;

#pragma unroll
  for (int i = 0; i < 4; ++i) {
    const int ch = wv * 4 + i;
    const int cc = ch >> 1;
    const int trow = (ch & 1) * 64 + lane;
    gl_lds16(Kh + (size_t)(t0 + trow) * KQVS + cc * 8, smem + 16384 + ch * 1024);
  }
#pragma unroll
  for (int i = 0; i < 2; ++i) {
    const int ch = wv * 2 + i;
    gl_lds16(Qh + (size_t)lane * KQVS + ch * 8, smem + ch * 1024);
  }
  {
    uint4 vr0[2];
    v_load(vr0, Vh, 0, tid);
    vt_write((u16*)(smem + 8192), vr0, tid);
  }
  __syncthreads();

  bf16x8 kf[4];
  {
    const u16* Ksp = (const u16*)(smem + 16384);
#pragma unroll
    for (int kk = 0; kk < 4; ++kk)
      kf[kk] = *(const bf16x8*)(Ksp + ((kk * 2 + hh) * 128 + wv * 32 + l31) * 8);
  }
  __syncthreads();

  f32x16 oa0 = {}, oa1 = {};
  float l_run = 0.f;

#pragma unroll 1
  for (int st = 0; st < nst; ++st) {
    const int cur = st & 1;
    const int s0 = st * 64;
    const bool pref = (st + 1 < nst);
    uint4 vr[2];
    if (pref) {
      v_load(vr, Vh, s0 + 64, tid);
#pragma unroll
      for (int i = 0; i < 2; ++i) {
        const int ch = wv * 2 + i;
        gl_lds16(Qh + (size_t)(s0 + 64 + lane) * KQVS + ch * 8,
                 smem + (cur ^ 1) * 16384 + ch * 1024);
      }
    }

    const bool active = (s0 <= t0w + 31);
    f32x16 sa0 = {}, sa1 = {};
    if (active) {
      if (pref) {
        asm volatile("s_waitcnt vmcnt(4)" ::: "memory");
      } else {
        asm volatile("s_waitcnt vmcnt(0)" ::: "memory");
      }
      __builtin_amdgcn_sched_barrier(0);

      const u16* qb = (const u16*)(smem + cur * 16384);
      __builtin_amdgcn_s_setprio(1);
#pragma unroll
      for (int kk = 0; kk < 4; ++kk) {
        bf16x8 a0 = *(const bf16x8*)(qb + ((kk * 2 + hh) * 64 + l31) * 8);
        bf16x8 a1 = *(const bf16x8*)(qb + ((kk * 2 + hh) * 64 + 32 + l31) * 8);
        sa0 = MFMA32(a0, kf[kk], sa0);
        sa1 = MFMA32(a1, kf[kk], sa1);
      }
      __builtin_amdgcn_s_setprio(0);

      if (s0 + 63 > t0w) {
#pragma unroll
        for (int r = 0; r < 16; ++r) {
          const int rowloc = (r & 3) + 8 * (r >> 2) + rb4;
          if (s0 + rowloc > tl) sa0[r] = NEG;
          if (s0 + 32 + rowloc > tl) sa1[r] = NEG;
        }
      }

#pragma unroll
      for (int r = 0; r < 16; ++r) {
        sa0[r] = fast_exp2(sa0[r] * SCL);
        sa1[r] = fast_exp2(sa1[r] * SCL);
      }
      float rsA = ((sa0[0] + sa0[1]) + (sa0[2] + sa0[3])) +
                  ((sa0[4] + sa0[5]) + (sa0[6] + sa0[7]));
      float rsB = ((sa0[8] + sa0[9]) + (sa0[10] + sa0[11])) +
                  ((sa0[12] + sa0[13]) + (sa0[14] + sa0[15]));
      float rsC = ((sa1[0] + sa1[1]) + (sa1[2] + sa1[3])) +
                  ((sa1[4] + sa1[5]) + (sa1[6] + sa1[7]));
      float rsD = ((sa1[8] + sa1[9]) + (sa1[10] + sa1[11])) +
                  ((sa1[12] + sa1[13]) + (sa1[14] + sa1[15]));
      float rs = (rsA + rsB) + (rsC + rsD);
      rs += __shfl_xor(rs, 32);
      l_run += rs;
    }

    if (pref) vt_write((u16*)(smem + (cur ^ 1) * 16384 + 8192), vr, tid);

    if (active) {
      const u16* vb = (const u16*)(smem + cur * 16384 + 8192);
      __builtin_amdgcn_s_setprio(1);
#define PV_WINDOW(P, r0, w)                                                   \
  {                                                                           \
    uint32_t dA = cvt_pk_bf16(P[r0 + 0], P[r0 + 1]);                          \
    uint32_t dB = cvt_pk_bf16(P[r0 + 2], P[r0 + 3]);                          \
    uint32_t dC = cvt_pk_bf16(P[r0 + 4], P[r0 + 5]);                          \
    uint32_t dD = cvt_pk_bf16(P[r0 + 6], P[r0 + 7]);                          \
    uint32_t sdA = (uint32_t)__shfl_xor((int)dA, 32);                         \
    uint32_t sdB = (uint32_t)__shfl_xor((int)dB, 32);                         \
    uint32_t sdC = (uint32_t)__shfl_xor((int)dC, 32);                         \
    uint32_t sdD = (uint32_t)__shfl_xor((int)dD, 32);                         \
    union { uint32_t u[4]; bf16x8 v; } af;                                    \
    af.u[0] = lolane ? dA : sdC;                                              \
    af.u[1] = lolane ? dB : sdD;                                              \
    af.u[2] = lolane ? sdA : dC;                                              \
    af.u[3] = lolane ? sdB : dD;                                              \
    bf16x8 bv0 = *(const bf16x8*)(vb + ((2 * (w) + hh) * 64 + l31) * 8);      \
    bf16x8 bv1 = *(const bf16x8*)(vb + ((2 * (w) + hh) * 64 + 32 + l31) * 8); \
    oa0 = MFMA32(af.v, bv0, oa0);                                             \
    oa1 = MFMA32(af.v, bv1, oa1);                                             \
  }
      PV_WINDOW(sa0, 0, 0)
      PV_WINDOW(sa0, 8, 1)
      PV_WINDOW(sa1, 0, 2)
      PV_WINDOW(sa1, 8, 3)
#undef PV_WINDOW
      __builtin_amdgcn_s_setprio(0);
    }

    asm volatile("s_waitcnt lgkmcnt(0)" ::: "memory");
    __builtin_amdgcn_s_barrier();
  }

  {
    const float inv = 1.0f / l_run;
#pragma unroll
    for (int r = 0; r < 16; ++r) {
      const int rowloc = (r & 3) + 8 * (r >> 2) + rb4;
      const float ir = __shfl(inv, rowloc);
      const int trow = t0w + rowloc;
      Oh[(size_t)trow * 1024 + l31] = f32_to_bf16_rne(oa0[r] * ir);
      Oh[(size_t)trow * 1024 + 32 + l31] = f32_to_bf16_rne(oa1[r] * ir);
    }
  }
}

// ---------------------------------------------------------------- launch
extern "C" void kernel_launch(void* const* d_in, const int* in_sizes, int n_in,
                              void* d_out, int out_size, void* d_ws, size_t ws_size,
                              hipStream_t stream) {
  (void)in_sizes; (void)n_in; (void)out_size; (void)ws_size;
  const float* x  = (const float*)d_in[0];
  const float* Wk = (const float*)d_in[1];
  const float* Wq = (const float*)d_in[2];
  const float* Wv = (const float*)d_in[3];
  const float* Wo = (const float*)d_in[4];
  const float* bo = (const float*)d_in[5];
  float* out = (float*)d_out;

  char* ws = (char*)d_ws;
  u16* xb   = (u16*)(ws);                       // 16MB (x cast, later attn-out)
  u16* kqv  = (u16*)(ws + ((size_t)16 << 20));  // 48MB [8192 x 3072] K|Q|V
  u16* wqkv = (u16*)(ws + ((size_t)64 << 20));  // 6MB  [3072 x 1024]
  u16* wob  = (u16*)(ws + ((size_t)70 << 20));  // 2MB -> 72MB total

  cast_all_kernel<<<dim3(12288), 256, 0, stream>>>(x, Wk, Wq, Wv, Wo, xb, wqkv, wob);

  // fused K/Q/V projection: [8192,3072] = [8192,1024] x [3072,1024]^T
  // 256^2 8-phase kernel: 32x12 = 384 blocks (8 XCD x 48), 512 threads
  gemm256_kernel<<<dim3(384), 512, 0, stream>>>(xb, wqkv, kqv, 8192, 3072, 1024);

  // attention (writes into xb)
  attn_kernel<<<dim3(1024), 256, 0, stream>>>(kqv, xb);

  // final projection + bias, f32 out
  gemm_bt_kernel<1><<<dim3(8, 64), 256, 0, stream>>>(xb, wob, out, bo, 8192, 1024, 1024);
}